// Round 1
// baseline (1242.371 us; speedup 1.0000x reference)
//
#include <hip/hip_runtime.h>

#define N_IMG 16
#define C_IN  128
#define H_IMG 64
#define W_IMG 64
#define K_OUT 256
#define CTILE 16
#define KTILE 64

// Block: 256 threads. Each thread owns 2 out-channels x 8 x-positions.
// Grid: n * y * (K/64) = 16*64*4 = 4096 blocks.
__global__ __launch_bounds__(256, 3)
void conv3x3_f32_kernel(const float* __restrict__ x,
                        const float* __restrict__ w,
                        float* __restrict__ out) {
    __shared__ float xs[CTILE][3][72];       // [c][row][col(-1..64 -> 0..65)], pad to 72
    __shared__ float ws[CTILE][9][KTILE];    // [c][tap][k]

    const int t  = threadIdx.x;
    const int kt = blockIdx.x & 3;           // k-tile index (0..3)
    const int y  = (blockIdx.x >> 2) & 63;   // output row
    const int n  = blockIdx.x >> 8;          // image

    const int k2   = t >> 3;                 // 0..31
    const int xg   = t & 7;                  // 0..7
    const int kloc = k2 * 2;                 // local k: 0,2,..,62
    const int x0   = xg * 8;                 // first of 8 output x positions

    float acc0[8] = {0.f,0.f,0.f,0.f,0.f,0.f,0.f,0.f};
    float acc1[8] = {0.f,0.f,0.f,0.f,0.f,0.f,0.f,0.f};

    const int k0 = kt * KTILE;

    for (int c0 = 0; c0 < C_IN; c0 += CTILE) {
        // ---- stage x tile: CTILE x 3 rows x 66 cols (zero-padded halo) ----
        for (int idx = t; idx < CTILE * 3 * 66; idx += 256) {
            int col = idx % 66;
            int rc  = idx / 66;
            int r   = rc % 3;
            int c   = rc / 3;
            int gx  = col - 1;
            int gy  = y - 1 + r;
            float v = 0.f;
            if ((unsigned)gx < (unsigned)W_IMG && (unsigned)gy < (unsigned)H_IMG)
                v = x[(((n * C_IN) + c0 + c) * H_IMG + gy) * W_IMG + gx];
            xs[c][r][col] = v;
        }
        // ---- stage weights: KTILE x CTILE x 9 ----
        for (int idx = t; idx < KTILE * CTILE * 9; idx += 256) {
            int tap = idx % 9;
            int ck  = idx / 9;
            int c   = ck % CTILE;
            int k   = ck / CTILE;
            ws[c][tap][k] = w[((k0 + k) * C_IN + c0 + c) * 9 + tap];
        }
        __syncthreads();

        // ---- compute ----
        #pragma unroll 2
        for (int c = 0; c < CTILE; ++c) {
            #pragma unroll
            for (int r = 0; r < 3; ++r) {
                float xr[10];
                #pragma unroll
                for (int i = 0; i < 10; ++i) xr[i] = xs[c][r][x0 + i];
                #pragma unroll
                for (int s = 0; s < 3; ++s) {
                    float w0 = ws[c][r * 3 + s][kloc];
                    float w1 = ws[c][r * 3 + s][kloc + 1];
                    #pragma unroll
                    for (int i = 0; i < 8; ++i) {
                        acc0[i] = fmaf(w0, xr[i + s], acc0[i]);
                        acc1[i] = fmaf(w1, xr[i + s], acc1[i]);
                    }
                }
            }
        }
        __syncthreads();
    }

    // ---- epilogue: 2 k x 8 consecutive x, coalesced within k ----
    float* o0 = &out[(((n * K_OUT) + k0 + kloc) * H_IMG + y) * W_IMG + x0];
    float* o1 = o0 + H_IMG * W_IMG;
    #pragma unroll
    for (int i = 0; i < 8; ++i) o0[i] = acc0[i];
    #pragma unroll
    for (int i = 0; i < 8; ++i) o1[i] = acc1[i];
}

extern "C" void kernel_launch(void* const* d_in, const int* in_sizes, int n_in,
                              void* d_out, int out_size, void* d_ws, size_t ws_size,
                              hipStream_t stream) {
    const float* x = (const float*)d_in[0];
    const float* w = (const float*)d_in[1];
    float* out = (float*)d_out;
    (void)in_sizes; (void)n_in; (void)out_size; (void)d_ws; (void)ws_size;

    dim3 grid(N_IMG * H_IMG * (K_OUT / KTILE));  // 4096
    dim3 block(256);
    conv3x3_f32_kernel<<<grid, block, 0, stream>>>(x, w, out);
}

// Round 2
// 152.398 us; speedup vs baseline: 8.1521x; 8.1521x over previous
//
#include <hip/hip_runtime.h>
#include <hip/hip_bf16.h>
#include <stdint.h>

typedef short bf16x8 __attribute__((ext_vector_type(8)));
typedef float f32x4 __attribute__((ext_vector_type(4)));

#define N_IMG 16
#define C_IN  128
#define H_IMG 64
#define W_IMG 64
#define K_OUT 256

// ws layout: xb = padded NHWC bf16 [16][66][66][128], then wb = [9][256][128] bf16
#define XB_BYTES (16ull*66*66*128*2)       // 17,842,176
#define WB_BYTES (9ull*256*128*2)          //    589,824
#define WS_NEED  (XB_BYTES + WB_BYTES)

// XOR swizzle on LDS byte address: slot bits (4-5) ^= bits (7-8)
#define SWZ(L) ((L) ^ ((((L) >> 7) & 3) << 4))

__device__ __forceinline__ void gload16(void* lds, const void* g) {
    __builtin_amdgcn_global_load_lds(
        (const __attribute__((address_space(1))) void*)g,
        (__attribute__((address_space(3))) void*)lds, 16, 0, 0);
}

// ---------------- transform_w: w[k][c][tap] fp32 -> wb[tap][k][c] bf16 ----------------
__global__ void transform_w_kernel(const float* __restrict__ w,
                                   __hip_bfloat16* __restrict__ wb) {
    __shared__ float lw[1152];
    const int kg = blockIdx.x;          // 0..255
    const int t  = threadIdx.x;
    for (int e = t; e < 1152; e += 256) lw[e] = w[kg * 1152 + e];
    __syncthreads();
    for (int e = t; e < 1152; e += 256) {
        int tap = e >> 7;               // 0..8
        int c   = e & 127;
        wb[(tap * 256 + kg) * 128 + c] = __float2bfloat16(lw[c * 9 + tap]);
    }
}

// ------- transform_x: x NCHW fp32 -> xb padded NHWC bf16 [n][yt][xt][c], halo=0 -------
__global__ void transform_x_kernel(const float* __restrict__ x,
                                   __hip_bfloat16* __restrict__ xb) {
    __shared__ uint16_t xsT[64 * 130];  // [gx][c], stride 130 (odd words -> no conflicts)
    const int b  = blockIdx.x;          // 16*66
    const int yt = b % 66;
    const int n  = b / 66;
    const int t  = threadIdx.x;
    const bool interior_row = (yt >= 1 && yt <= 64);

    if (interior_row) {
        const float* src = x + (size_t)n * 524288 + (size_t)(yt - 1) * 64;
        for (int e = t; e < 8192; e += 256) {
            int c = e >> 6, gx = e & 63;
            __hip_bfloat16 h = __float2bfloat16(src[c * 4096 + gx]);
            xsT[gx * 130 + c] = *(const uint16_t*)&h;
        }
    }
    __syncthreads();

    uint4* dst = (uint4*)((char*)xb + ((size_t)(n * 66 + yt)) * 66 * 256);
    for (int ch = t; ch < 1056; ch += 256) {    // 66*128*2B / 16B
        int xt = ch >> 4;
        int c0 = (ch & 15) * 8;
        uint4 val = make_uint4(0u, 0u, 0u, 0u);
        if (interior_row && xt >= 1 && xt <= 64) {
            const uint16_t* p = &xsT[(xt - 1) * 130 + c0];
            val.x = (uint32_t)p[0] | ((uint32_t)p[1] << 16);
            val.y = (uint32_t)p[2] | ((uint32_t)p[3] << 16);
            val.z = (uint32_t)p[4] | ((uint32_t)p[5] << 16);
            val.w = (uint32_t)p[6] | ((uint32_t)p[7] << 16);
        }
        dst[ch] = val;
    }
}

// ---------------- main conv: implicit GEMM, 16x16x32 bf16 MFMA ----------------
// block: (n, y, kt) -> 64 out-channels x 64 x. 4 waves, each 32k x 32x (2x2 frags).
// LDS: xs = [row 0..2][xt 0..65][c-chunk 32] (64B per (row,xt)) = 12672 B (792 chunks)
//      ws = [tap 0..8][k 0..63][c-chunk 32]                     = 36864 B (2304 chunks)
__global__ __launch_bounds__(256, 3)
void conv3x3_mfma_kernel(const __hip_bfloat16* __restrict__ xbh,
                         const __hip_bfloat16* __restrict__ wbh,
                         float* __restrict__ out) {
    __shared__ uint4 smem[3096];        // 49536 B
    char* lds = (char*)smem;
    const char* xg = (const char*)xbh;
    const char* wg = (const char*)wbh;

    const int t  = threadIdx.x;
    const int b  = blockIdx.x;
    const int kt = b & 3;
    const int y  = (b >> 2) & 63;
    const int n  = b >> 8;

    const int lane = t & 63;
    const int wv   = t >> 6;
    const int wr   = wv >> 1;           // k-half
    const int wc   = wv & 1;            // x-half
    const int lm   = lane & 15;
    const int g    = lane >> 4;

    const int kbase = wr * 32;
    const int xbase = wc * 32;

    f32x4 acc[2][2];
    #pragma unroll
    for (int i = 0; i < 2; ++i)
        #pragma unroll
        for (int j = 0; j < 2; ++j)
            acc[i][j] = (f32x4){0.f, 0.f, 0.f, 0.f};

    for (int cc = 0; cc < 4; ++cc) {
        // ---- stage X tile: 792 chunks, source pre-swizzled ----
        for (int ch = t; ch < 792; ch += 256) {
            int sc   = ch ^ ((ch >> 3) & 3);
            int coct = sc & 3;
            int xl   = sc >> 2;                 // row*66 + xt
            int row  = xl / 66;
            int xt   = xl - row * 66;
            const char* src = xg + (((size_t)(n * 66 + y + row) * 66 + xt) * 256
                                    + cc * 64 + coct * 16);
            gload16(lds + ch * 16, src);
        }
        // ---- stage W tile: 2304 chunks ----
        for (int ch = t; ch < 2304; ch += 256) {
            int sc   = ch ^ ((ch >> 3) & 3);
            int coct = sc & 3;
            int k    = (sc >> 2) & 63;
            int tap  = sc >> 8;
            const char* src = wg + ((size_t)(tap * 256 + kt * 64 + k) * 256
                                    + cc * 64 + coct * 16);
            gload16(lds + 792 * 16 + ch * 16, src);
        }
        __syncthreads();   // compiler emits vmcnt(0) drain before s_barrier

        const char* xsb = lds;
        const char* wsb = lds + 792 * 16;
        #pragma unroll
        for (int r = 0; r < 3; ++r) {
            #pragma unroll
            for (int s = 0; s < 3; ++s) {
                const int tap = r * 3 + s;
                int LA0 = (tap * 64 + kbase + 0  + lm) * 64 + g * 16;
                int LA1 = (tap * 64 + kbase + 16 + lm) * 64 + g * 16;
                bf16x8 a0 = *(const bf16x8*)(wsb + SWZ(LA0));
                bf16x8 a1 = *(const bf16x8*)(wsb + SWZ(LA1));
                int xl0 = r * 66 + xbase + s + lm;  // tile xt = x + s
                int LB0 = (xl0 * 64)        + g * 16;
                int LB1 = ((xl0 + 16) * 64) + g * 16;
                bf16x8 b0 = *(const bf16x8*)(xsb + SWZ(LB0));
                bf16x8 b1 = *(const bf16x8*)(xsb + SWZ(LB1));
                acc[0][0] = __builtin_amdgcn_mfma_f32_16x16x32_bf16(a0, b0, acc[0][0], 0, 0, 0);
                acc[0][1] = __builtin_amdgcn_mfma_f32_16x16x32_bf16(a0, b1, acc[0][1], 0, 0, 0);
                acc[1][0] = __builtin_amdgcn_mfma_f32_16x16x32_bf16(a1, b0, acc[1][0], 0, 0, 0);
                acc[1][1] = __builtin_amdgcn_mfma_f32_16x16x32_bf16(a1, b1, acc[1][1], 0, 0, 0);
            }
        }
        __syncthreads();
    }

    // ---- epilogue: D row = (l>>4)*4 + reg, col = l&15 (verified layout) ----
    #pragma unroll
    for (int m = 0; m < 2; ++m) {
        #pragma unroll
        for (int nn = 0; nn < 2; ++nn) {
            const int xcol = xbase + nn * 16 + lm;
            #pragma unroll
            for (int r4 = 0; r4 < 4; ++r4) {
                int k = kt * 64 + kbase + m * 16 + g * 4 + r4;
                out[(((size_t)(n * 256 + k)) * 64 + y) * 64 + xcol] = acc[m][nn][r4];
            }
        }
    }
}

// ---------------- fallback (round-1, fp32, known-correct) ----------------
__global__ __launch_bounds__(256, 3)
void conv3x3_f32_kernel(const float* __restrict__ x,
                        const float* __restrict__ w,
                        float* __restrict__ out) {
    __shared__ float xs[16][3][72];
    __shared__ float ws[16][9][64];

    const int t  = threadIdx.x;
    const int kt = blockIdx.x & 3;
    const int y  = (blockIdx.x >> 2) & 63;
    const int n  = blockIdx.x >> 8;

    const int k2   = t >> 3;
    const int xg   = t & 7;
    const int kloc = k2 * 2;
    const int x0   = xg * 8;

    float acc0[8] = {0.f,0.f,0.f,0.f,0.f,0.f,0.f,0.f};
    float acc1[8] = {0.f,0.f,0.f,0.f,0.f,0.f,0.f,0.f};

    const int k0 = kt * 64;

    for (int c0 = 0; c0 < C_IN; c0 += 16) {
        for (int idx = t; idx < 16 * 3 * 66; idx += 256) {
            int col = idx % 66;
            int rc  = idx / 66;
            int r   = rc % 3;
            int c   = rc / 3;
            int gx  = col - 1;
            int gy  = y - 1 + r;
            float v = 0.f;
            if ((unsigned)gx < (unsigned)W_IMG && (unsigned)gy < (unsigned)H_IMG)
                v = x[(((n * C_IN) + c0 + c) * H_IMG + gy) * W_IMG + gx];
            xs[c][r][col] = v;
        }
        for (int idx = t; idx < 64 * 16 * 9; idx += 256) {
            int tap = idx % 9;
            int ck  = idx / 9;
            int c   = ck % 16;
            int k   = ck / 16;
            ws[c][tap][k] = w[((k0 + k) * C_IN + c0 + c) * 9 + tap];
        }
        __syncthreads();

        #pragma unroll 2
        for (int c = 0; c < 16; ++c) {
            #pragma unroll
            for (int r = 0; r < 3; ++r) {
                float xr[10];
                #pragma unroll
                for (int i = 0; i < 10; ++i) xr[i] = xs[c][r][x0 + i];
                #pragma unroll
                for (int s = 0; s < 3; ++s) {
                    float w0 = ws[c][r * 3 + s][kloc];
                    float w1 = ws[c][r * 3 + s][kloc + 1];
                    #pragma unroll
                    for (int i = 0; i < 8; ++i) {
                        acc0[i] = fmaf(w0, xr[i + s], acc0[i]);
                        acc1[i] = fmaf(w1, xr[i + s], acc1[i]);
                    }
                }
            }
        }
        __syncthreads();
    }

    float* o0 = &out[(((n * K_OUT) + k0 + kloc) * H_IMG + y) * W_IMG + x0];
    float* o1 = o0 + H_IMG * W_IMG;
    #pragma unroll
    for (int i = 0; i < 8; ++i) o0[i] = acc0[i];
    #pragma unroll
    for (int i = 0; i < 8; ++i) o1[i] = acc1[i];
}

extern "C" void kernel_launch(void* const* d_in, const int* in_sizes, int n_in,
                              void* d_out, int out_size, void* d_ws, size_t ws_size,
                              hipStream_t stream) {
    const float* x = (const float*)d_in[0];
    const float* w = (const float*)d_in[1];
    float* out = (float*)d_out;
    (void)in_sizes; (void)n_in; (void)out_size;

    if (ws_size >= WS_NEED) {
        __hip_bfloat16* xb = (__hip_bfloat16*)d_ws;
        __hip_bfloat16* wb = (__hip_bfloat16*)((char*)d_ws + XB_BYTES);
        transform_w_kernel<<<256, 256, 0, stream>>>(w, wb);
        transform_x_kernel<<<16 * 66, 256, 0, stream>>>(x, xb);
        conv3x3_mfma_kernel<<<4096, 256, 0, stream>>>(xb, wb, out);
    } else {
        conv3x3_f32_kernel<<<4096, 256, 0, stream>>>(x, w, out);
    }
}

// Round 3
// 135.035 us; speedup vs baseline: 9.2004x; 1.1286x over previous
//
#include <hip/hip_runtime.h>
#include <hip/hip_bf16.h>
#include <stdint.h>

typedef short bf16x8 __attribute__((ext_vector_type(8)));
typedef float f32x16 __attribute__((ext_vector_type(16)));

#define N_IMG 16
#define C_IN  128
#define H_IMG 64
#define W_IMG 64
#define K_OUT 256

// ws layout: xb = padded NHWC bf16 [16][66][66][128], then wb = [9][256][128] bf16
#define XB_BYTES (16ull*66*66*128*2)       // 17,842,176
#define WB_BYTES (9ull*256*128*2)          //    589,824
#define WS_NEED  (XB_BYTES + WB_BYTES)

#define LDSX_BYTES (6*66*256)              // 101,376 (X tile, resident)
#define WCH_BYTES  16384                   // one W chunk: 256k x 32c x 2B
#define LDS_TOTAL  (LDSX_BYTES + 3*WCH_BYTES)   // 150,528

__device__ __forceinline__ void gload16(void* lds, const void* g) {
    __builtin_amdgcn_global_load_lds(
        (const __attribute__((address_space(1))) void*)g,
        (__attribute__((address_space(3))) void*)lds, 16, 0, 0);
}

// ---------------- transform_w: w[k][c][tap] fp32 -> wb[tap][k][c] bf16 ----------------
__global__ void transform_w_kernel(const float* __restrict__ w,
                                   __hip_bfloat16* __restrict__ wb) {
    __shared__ float lw[1152];
    const int kg = blockIdx.x;          // 0..255
    const int t  = threadIdx.x;
    for (int e = t; e < 1152; e += 256) lw[e] = w[kg * 1152 + e];
    __syncthreads();
    for (int e = t; e < 1152; e += 256) {
        int tap = e >> 7;               // 0..8
        int c   = e & 127;
        wb[(tap * 256 + kg) * 128 + c] = __float2bfloat16(lw[c * 9 + tap]);
    }
}

// ------- transform_x: x NCHW fp32 -> xb padded NHWC bf16 [n][yt][xt][c], halo=0 -------
__device__ __forceinline__ uint32_t pack2(float a, float b) {
    __hip_bfloat16 ha = __float2bfloat16(a), hb = __float2bfloat16(b);
    return (uint32_t)*(uint16_t*)&ha | ((uint32_t)*(uint16_t*)&hb << 16);
}

__global__ void transform_x_kernel(const float* __restrict__ x,
                                   __hip_bfloat16* __restrict__ xb) {
    // xsT: rows = gx (0..63), 68 dwords/row (272B, 16B-aligned); col j = c-pair {2j,2j+1}
    __shared__ __align__(16) uint32_t xsT[64 * 68];
    const int b  = blockIdx.x;          // 16*66
    const int yt = b % 66;
    const int n  = b / 66;
    const int t  = threadIdx.x;
    const bool interior = (yt >= 1 && yt <= 64);

    if (interior) {
        const float4* src = (const float4*)(x + (size_t)n * 524288 + (size_t)(yt - 1) * 64);
        #pragma unroll
        for (int it = 0; it < 4; ++it) {
            int e  = t + it * 256;      // 0..1023
            int c2 = e >> 4;            // 0..63 (c-pair)
            int x4 = e & 15;            // float4 index within row
            float4 va = src[(2 * c2) * 1024 + x4];
            float4 vb = src[(2 * c2 + 1) * 1024 + x4];
            int xr = x4 * 4;
            xsT[(xr + 0) * 68 + c2] = pack2(va.x, vb.x);
            xsT[(xr + 1) * 68 + c2] = pack2(va.y, vb.y);
            xsT[(xr + 2) * 68 + c2] = pack2(va.z, vb.z);
            xsT[(xr + 3) * 68 + c2] = pack2(va.w, vb.w);
        }
    }
    __syncthreads();

    uint4* dst = (uint4*)((char*)xb + (size_t)(n * 66 + yt) * 66 * 256);
    for (int ch = t; ch < 1056; ch += 256) {    // 66 xt * 16 uint4
        int xt = ch >> 4;
        int cp = ch & 15;
        uint4 val = make_uint4(0u, 0u, 0u, 0u);
        if (interior && xt >= 1 && xt <= 64)
            val = *(const uint4*)&xsT[(xt - 1) * 68 + cp * 4];
        dst[ch] = val;
    }
}

// ---------------- main conv: X-resident implicit GEMM, 32x32x16 bf16 MFMA ----------------
// Block: (n, y-quad) -> 256 k x 256 m (4 y x 64 x). 8 waves, each 64k x 128m (2x4 frags).
// K-loop: 36 chunks (tap 0..8 x cc 0..3); W chunk [256k][32c] triple-buffered, vmcnt(2).
__global__ __launch_bounds__(512, 2)
void conv3x3_mfma_kernel(const char* __restrict__ xg,
                         const char* __restrict__ wg,
                         float* __restrict__ out) {
    __shared__ uint4 smem[LDS_TOTAL / 16];
    char* lds  = (char*)smem;
    char* ldsW = lds + LDSX_BYTES;

    const int t    = threadIdx.x;
    const int b    = blockIdx.x;        // 0..255
    const int q    = b & 15;            // y-quad
    const int n    = b >> 4;
    const int lane = t & 63;
    const int wv   = t >> 6;
    const int lm   = lane & 31;
    const int hi   = lane >> 5;         // c-octet selector
    const int kb   = (wv >> 1) * 64;    // wave k-base (0/64/128/192)
    const int mb   = (wv & 1) * 128;    // wave m-base (0/128)

    // ---- thread-constant fragment addresses ----
    // W read: addr = krow*64 + ((ks*32 + hi*16) ^ ((krow&3)<<4))
    int addrW[2][2];
    #pragma unroll
    for (int kf = 0; kf < 2; ++kf) {
        int krow = kb + kf * 32 + lm;
        #pragma unroll
        for (int ks = 0; ks < 2; ++ks)
            addrW[kf][ks] = krow * 64 + ((ks * 32 + hi * 16) ^ ((krow & 3) << 4));
    }
    // X read: rc0[f] = yy*66 + x for m = mb + f*32 + lm
    int rc0[4];
    #pragma unroll
    for (int f = 0; f < 4; ++f) {
        int m = mb + f * 32 + lm;
        rc0[f] = (m >> 6) * 66 + (m & 63);
    }
    const int coffX0 = hi * 16;          // + ks*32 + cc*64 at use site

    // W staging per-thread constants (2 chunks of 16B per thread per W chunk)
    const int krow0 = t >> 2;
    const int woffA = krow0 * 256 + (((t & 3) ^ (krow0 & 3)) << 4);  // +32768 for second

    // ---- prologue: stage X (linear LDS dest, pre-swizzled source) ----
    const char* xsrc = xg + (size_t)(n * 66 + q * 4) * 66 * 256;
    for (int ch = t; ch < 6336; ch += 512) {
        int L = ch * 16;
        gload16(lds + L, xsrc + (L ^ (((L >> 8) & 7) << 4)));
    }
    // stage W[0] -> buf0, W[1] -> buf1
    #pragma unroll
    for (int jj = 0; jj < 2; ++jj) {
        const char* s = wg + (jj >> 2) * 65536 + (jj & 3) * 64;
        char* d = ldsW + jj * WCH_BYTES + t * 16;
        gload16(d, s + woffA);
        gload16(d + 8192, s + woffA + 32768);
    }
    asm volatile("s_waitcnt vmcnt(2)" ::: "memory");   // X + W0 done, W1 in flight
    __builtin_amdgcn_sched_barrier(0);
    __builtin_amdgcn_s_barrier();

    f32x16 acc[2][4];
    #pragma unroll
    for (int i = 0; i < 2; ++i)
        #pragma unroll
        for (int j = 0; j < 4; ++j)
            acc[i][j] = (f32x16)(0.f);

    int bR = 0;   // read buffer = j%3
    int bP = 2;   // prefetch buffer = (j+2)%3
    for (int j = 0; j < 36; ++j) {
        // ---- prefetch W[j+2] (wrapped; tail iterations load junk, never read) ----
        {
            int jj = j + 2; if (jj >= 36) jj -= 36;
            int tap2 = jj >> 2, cc2 = jj & 3;
            const char* s = wg + tap2 * 65536 + cc2 * 64;
            char* d = ldsW + bP * WCH_BYTES + t * 16;
            gload16(d, s + woffA);
            gload16(d + 8192, s + woffA + 32768);
        }
        // ---- compute chunk j: tap = j>>2, cc = j&3 ----
        const int tap = j >> 2;
        const int cc  = j & 3;
        const int r   = (tap >= 6) ? 2 : (tap >= 3 ? 1 : 0);
        const int s_  = tap - r * 3;
        const int rs66 = r * 66 + s_;
        const char* wbuf = ldsW + bR * WCH_BYTES;

        __builtin_amdgcn_s_setprio(1);
        #pragma unroll
        for (int ks = 0; ks < 2; ++ks) {
            bf16x8 a0 = *(const bf16x8*)(wbuf + addrW[0][ks]);
            bf16x8 a1 = *(const bf16x8*)(wbuf + addrW[1][ks]);
            const int co = cc * 64 + ks * 32 + coffX0;
            #pragma unroll
            for (int f = 0; f < 4; ++f) {
                int rc = rc0[f] + rs66;
                int L  = rc * 256 + (co ^ ((rc & 7) << 4));
                bf16x8 bfr = *(const bf16x8*)(lds + L);
                acc[0][f] = __builtin_amdgcn_mfma_f32_32x32x16_bf16(a0, bfr, acc[0][f], 0, 0, 0);
                acc[1][f] = __builtin_amdgcn_mfma_f32_32x32x16_bf16(a1, bfr, acc[1][f], 0, 0, 0);
            }
        }
        __builtin_amdgcn_s_setprio(0);

        asm volatile("s_waitcnt vmcnt(2)" ::: "memory");  // W[j+1] landed; W[j+2] in flight
        __builtin_amdgcn_sched_barrier(0);
        __builtin_amdgcn_s_barrier();

        bR = (bR == 2) ? 0 : bR + 1;
        bP = (bP == 2) ? 0 : bP + 1;
    }

    // ---- epilogue: D row(k) = (reg&3)+8*(reg>>2)+4*hi, col(m) = lm ----
    const int y0 = q * 4;
    #pragma unroll
    for (int kf = 0; kf < 2; ++kf) {
        const int kbase2 = kb + kf * 32 + 4 * hi;
        #pragma unroll
        for (int f = 0; f < 4; ++f) {
            int m  = mb + f * 32 + lm;
            int yy = m >> 6;
            int xx = m & 63;
            float* op = out + (((size_t)(n * 256 + kbase2) * 64) + y0 + yy) * 64 + xx;
            #pragma unroll
            for (int reg = 0; reg < 16; ++reg) {
                int koff = (reg & 3) + 8 * (reg >> 2);
                op[(size_t)koff * 4096] = acc[kf][f][reg];
            }
        }
    }
}

// ---------------- fallback (fp32, known-correct) ----------------
__global__ __launch_bounds__(256, 3)
void conv3x3_f32_kernel(const float* __restrict__ x,
                        const float* __restrict__ w,
                        float* __restrict__ out) {
    __shared__ float xs[16][3][72];
    __shared__ float ws[16][9][64];

    const int t  = threadIdx.x;
    const int kt = blockIdx.x & 3;
    const int y  = (blockIdx.x >> 2) & 63;
    const int n  = blockIdx.x >> 8;

    const int k2   = t >> 3;
    const int xg   = t & 7;
    const int kloc = k2 * 2;
    const int x0   = xg * 8;

    float acc0[8] = {0.f,0.f,0.f,0.f,0.f,0.f,0.f,0.f};
    float acc1[8] = {0.f,0.f,0.f,0.f,0.f,0.f,0.f,0.f};

    const int k0 = kt * 64;

    for (int c0 = 0; c0 < C_IN; c0 += 16) {
        for (int idx = t; idx < 16 * 3 * 66; idx += 256) {
            int col = idx % 66;
            int rc  = idx / 66;
            int r   = rc % 3;
            int c   = rc / 3;
            int gx  = col - 1;
            int gy  = y - 1 + r;
            float v = 0.f;
            if ((unsigned)gx < (unsigned)W_IMG && (unsigned)gy < (unsigned)H_IMG)
                v = x[(((n * C_IN) + c0 + c) * H_IMG + gy) * W_IMG + gx];
            xs[c][r][col] = v;
        }
        for (int idx = t; idx < 64 * 16 * 9; idx += 256) {
            int tap = idx % 9;
            int ck  = idx / 9;
            int c   = ck % 16;
            int k   = ck / 16;
            ws[c][tap][k] = w[((k0 + k) * C_IN + c0 + c) * 9 + tap];
        }
        __syncthreads();

        #pragma unroll 2
        for (int c = 0; c < 16; ++c) {
            #pragma unroll
            for (int r = 0; r < 3; ++r) {
                float xr[10];
                #pragma unroll
                for (int i = 0; i < 10; ++i) xr[i] = xs[c][r][x0 + i];
                #pragma unroll
                for (int s = 0; s < 3; ++s) {
                    float w0 = ws[c][r * 3 + s][kloc];
                    float w1 = ws[c][r * 3 + s][kloc + 1];
                    #pragma unroll
                    for (int i = 0; i < 8; ++i) {
                        acc0[i] = fmaf(w0, xr[i + s], acc0[i]);
                        acc1[i] = fmaf(w1, xr[i + s], acc1[i]);
                    }
                }
            }
        }
        __syncthreads();
    }

    float* o0 = &out[(((n * K_OUT) + k0 + kloc) * H_IMG + y) * W_IMG + x0];
    float* o1 = o0 + H_IMG * W_IMG;
    #pragma unroll
    for (int i = 0; i < 8; ++i) o0[i] = acc0[i];
    #pragma unroll
    for (int i = 0; i < 8; ++i) o1[i] = acc1[i];
}

extern "C" void kernel_launch(void* const* d_in, const int* in_sizes, int n_in,
                              void* d_out, int out_size, void* d_ws, size_t ws_size,
                              hipStream_t stream) {
    const float* x = (const float*)d_in[0];
    const float* w = (const float*)d_in[1];
    float* out = (float*)d_out;
    (void)in_sizes; (void)n_in; (void)out_size;

    if (ws_size >= WS_NEED) {
        __hip_bfloat16* xb = (__hip_bfloat16*)d_ws;
        __hip_bfloat16* wb = (__hip_bfloat16*)((char*)d_ws + XB_BYTES);
        transform_w_kernel<<<256, 256, 0, stream>>>(w, wb);
        transform_x_kernel<<<16 * 66, 256, 0, stream>>>(x, xb);
        conv3x3_mfma_kernel<<<256, 512, 0, stream>>>((const char*)xb, (const char*)wb, out);
    } else {
        conv3x3_f32_kernel<<<4096, 256, 0, stream>>>(x, w, out);
    }
}

// Round 5
// 132.915 us; speedup vs baseline: 9.3471x; 1.0159x over previous
//
#include <hip/hip_runtime.h>
#include <hip/hip_bf16.h>
#include <stdint.h>

typedef short bf16x8 __attribute__((ext_vector_type(8)));
typedef float f32x16 __attribute__((ext_vector_type(16)));

#define N_IMG 16
#define C_IN  128
#define H_IMG 64
#define W_IMG 64
#define K_OUT 256

// ws layout: xb = padded NHWC bf16 [16][66][66][128], then wb = [9][256][128] bf16
#define XB_BYTES (16ull*66*66*128*2)       // 17,842,176
#define WB_BYTES (9ull*256*128*2)          //    589,824
#define WS_NEED  (XB_BYTES + WB_BYTES)

#define LDSX_BYTES (6*66*256)              // 101,376 (X tile, resident)
#define WCH_BYTES  16384                   // one W chunk: 256k x 32c x 2B
#define LDS_TOTAL  (LDSX_BYTES + 3*WCH_BYTES)   // 150,528

__device__ __forceinline__ void gload16(void* lds, const void* g) {
    __builtin_amdgcn_global_load_lds(
        (const __attribute__((address_space(1))) void*)g,
        (__attribute__((address_space(3))) void*)lds, 16, 0, 0);
}

__device__ __forceinline__ uint32_t pack2(float a, float b) {
    __hip_bfloat16 ha = __float2bfloat16(a), hb = __float2bfloat16(b);
    return (uint32_t)*(uint16_t*)&ha | ((uint32_t)*(uint16_t*)&hb << 16);
}

// ---------------- fused prep: x -> padded NHWC bf16, w -> [tap][k][c] bf16 -------------
// blocks [0,1056): x rows.  blocks [1056,1312): w out-channel groups.
__global__ __launch_bounds__(256)
void transform_fused_kernel(const float* __restrict__ x, const float* __restrict__ w,
                            __hip_bfloat16* __restrict__ xb, __hip_bfloat16* __restrict__ wb) {
    __shared__ __align__(16) uint32_t xs[64 * 64];   // [row=x][cpair j], XOR-swizzled
    const int b = blockIdx.x;
    const int t = threadIdx.x;

    if (b < 1056) {
        const int yt = b % 66;
        const int n  = b / 66;
        const bool interior = (yt >= 1 && yt <= 64);

        if (interior) {
            const float4* src = (const float4*)(x + (size_t)n * 524288 + (size_t)(yt - 1) * 64);
            #pragma unroll
            for (int it = 0; it < 4; ++it) {
                const int x4 = t & 15;                 // float4 index in row (coalesced)
                const int j  = (t >> 4) + it * 16;     // c-pair 0..63
                float4 va = src[(2 * j) * 1024 + x4];
                float4 vb = src[(2 * j + 1) * 1024 + x4];
                const float* pa = (const float*)&va;
                const float* pb = (const float*)&vb;
                #pragma unroll
                for (int i = 0; i < 4; ++i) {
                    int row = x4 * 4 + i;
                    // swizzle key = (row>>2)&3 = x4&3 (varies across lanes -> 4-way max)
                    xs[row * 64 + (j ^ (((row >> 2) & 3) << 2))] = pack2(pa[i], pb[i]);
                }
            }
        }
        __syncthreads();

        uint4* dst = (uint4*)((char*)xb + (size_t)(n * 66 + yt) * 66 * 256);
        #pragma unroll
        for (int it = 0; it < 5; ++it) {
            int ch = t + it * 256;
            if (ch < 1056) {
                int xt = ch >> 4, u = ch & 15;
                uint4 val = make_uint4(0u, 0u, 0u, 0u);
                if (interior && xt >= 1 && xt <= 64) {
                    int row = xt - 1;
                    val = *(const uint4*)&xs[row * 64 + 4 * (u ^ ((row >> 2) & 3))];
                }
                dst[ch] = val;
            }
        }
    } else {
        // ---- w path: w[k][c][tap] fp32 -> wb[tap][k][c] bf16 ----
        const int kg = b - 1056;                       // 0..255
        #pragma unroll
        for (int it = 0; it < 5; ++it) {
            int e = t + it * 256;
            if (e < 1152) {
                int tap = e >> 7;                      // 0..8
                int c   = e & 127;
                wb[(tap * 256 + kg) * 128 + c] =
                    __float2bfloat16(w[kg * 1152 + c * 9 + tap]);
            }
        }
    }
}

// ---------------- main conv: X-resident implicit GEMM, 32x32x16 bf16 MFMA --------------
// Block: (n, y-quad) -> 256 k x 256 m (4 y x 64 x). 8 waves, each 64k x 128m (2x4 frags).
// K-loop: 36 chunks (tap x cc); W [256k][32c] triple-buffered vmcnt(2); X frags
// register-pipelined one chunk ahead (X LDS tile is read-only after prologue).
__global__ __launch_bounds__(512, 2)
void conv3x3_mfma_kernel(const char* __restrict__ xg,
                         const char* __restrict__ wg,
                         float* __restrict__ out) {
    __shared__ uint4 smem[LDS_TOTAL / 16];
    char* lds  = (char*)smem;
    char* ldsW = lds + LDSX_BYTES;

    const int t    = threadIdx.x;
    const int b    = blockIdx.x;        // 0..255
    const int q    = b & 15;            // y-quad
    const int n    = b >> 4;
    const int lane = t & 63;
    const int wv   = t >> 6;
    const int lm   = lane & 31;
    const int hi   = lane >> 5;         // c-octet selector
    const int kb   = (wv >> 1) * 64;    // wave k-base (0/64/128/192)
    const int mb   = (wv & 1) * 128;    // wave m-base (0/128)

    // W fragment addresses (swizzled to match staging)
    int addrW[2][2];
    #pragma unroll
    for (int kf = 0; kf < 2; ++kf) {
        int krow = kb + kf * 32 + lm;
        #pragma unroll
        for (int ks = 0; ks < 2; ++ks)
            addrW[kf][ks] = krow * 64 + ((ks * 32 + hi * 16) ^ ((krow & 3) << 4));
    }
    // X fragment row bases
    int rc0[4];
    #pragma unroll
    for (int f = 0; f < 4; ++f) {
        int m = mb + f * 32 + lm;
        rc0[f] = (m >> 6) * 66 + (m & 63);
    }

    // W staging constants (2x 16B per thread per W chunk)
    const int krow0 = t >> 2;
    const int woffA = krow0 * 256 + (((t & 3) ^ (krow0 & 3)) << 4);

    // ---- prologue: stage X (linear LDS dest, pre-swizzled source) ----
    const char* xsrc = xg + (size_t)(n * 66 + q * 4) * 66 * 256;
    for (int ch = t; ch < 6336; ch += 512) {
        int L = ch * 16;
        gload16(lds + L, xsrc + (L ^ (((L >> 8) & 7) << 4)));
    }
    // stage W[0] -> buf0, W[1] -> buf1
    #pragma unroll
    for (int jj = 0; jj < 2; ++jj) {
        const char* s = wg + (jj >> 2) * 65536 + (jj & 3) * 64;
        char* d = ldsW + jj * WCH_BYTES + t * 16;
        gload16(d, s + woffA);
        gload16(d + 8192, s + woffA + 32768);
    }
    asm volatile("s_waitcnt vmcnt(2)" ::: "memory");   // X + W0 done, W1 in flight
    __builtin_amdgcn_sched_barrier(0);
    __builtin_amdgcn_s_barrier();

    f32x16 acc[2][4];
    #pragma unroll
    for (int i = 0; i < 2; ++i)
        #pragma unroll
        for (int j = 0; j < 4; ++j)
            acc[i][j] = (f32x16)(0.f);

    int bR = 0;   // read buffer
    int bP = 2;   // prefetch buffer

    auto loadx = [&](bf16x8 (&X)[2][4], int jj) {
        int tap = jj >> 2, cc = jj & 3;
        int r   = (tap >= 6) ? 2 : (tap >= 3 ? 1 : 0);
        int s_  = tap - r * 3;
        int rs66 = r * 66 + s_;
        #pragma unroll
        for (int ks = 0; ks < 2; ++ks) {
            const int co = cc * 64 + ks * 32 + hi * 16;
            #pragma unroll
            for (int f = 0; f < 4; ++f) {
                int rc = rc0[f] + rs66;
                int L  = rc * 256 + (co ^ ((rc & 7) << 4));
                X[ks][f] = *(const bf16x8*)(lds + L);
            }
        }
    };

    auto chunk = [&](int j, bf16x8 (&XC)[2][4], bf16x8 (&XN)[2][4]) {
        // prefetch W[j+2] (wrapped; tail loads junk, never read)
        int jj2 = j + 2; if (jj2 >= 36) jj2 -= 36;
        {
            int tap2 = jj2 >> 2, cc2 = jj2 & 3;
            const char* s = wg + tap2 * 65536 + cc2 * 64;
            char* d = ldsW + bP * WCH_BYTES + t * 16;
            gload16(d, s + woffA);
            gload16(d + 8192, s + woffA + 32768);
        }
        // A (W) fragment reads for chunk j — only these gate the MFMAs
        const char* wbuf = ldsW + bR * WCH_BYTES;
        bf16x8 a[2][2];
        #pragma unroll
        for (int kf = 0; kf < 2; ++kf)
            #pragma unroll
            for (int ks = 0; ks < 2; ++ks)
                a[kf][ks] = *(const bf16x8*)(wbuf + addrW[kf][ks]);
        // X fragment prefetch for chunk j+1 (resident tile — no sync needed)
        int jn = j + 1; if (jn >= 36) jn -= 36;
        loadx(XN, jn);

        __builtin_amdgcn_s_setprio(1);
        #pragma unroll
        for (int ks = 0; ks < 2; ++ks) {
            #pragma unroll
            for (int f = 0; f < 4; ++f) {
                acc[0][f] = __builtin_amdgcn_mfma_f32_32x32x16_bf16(a[0][ks], XC[ks][f], acc[0][f], 0, 0, 0);
                acc[1][f] = __builtin_amdgcn_mfma_f32_32x32x16_bf16(a[1][ks], XC[ks][f], acc[1][f], 0, 0, 0);
            }
        }
        __builtin_amdgcn_s_setprio(0);

        asm volatile("s_waitcnt vmcnt(2)" ::: "memory");  // W[j+1] landed; W[j+2] in flight
        __builtin_amdgcn_sched_barrier(0);
        __builtin_amdgcn_s_barrier();

        bR = (bR == 2) ? 0 : bR + 1;
        bP = (bP == 2) ? 0 : bP + 1;
    };

    bf16x8 xA[2][4], xB[2][4];
    loadx(xA, 0);
    for (int j = 0; j < 36; j += 2) {
        chunk(j,     xA, xB);
        chunk(j + 1, xB, xA);
    }

    // ---- epilogue: D row(k) = (reg&3)+8*(reg>>2)+4*hi, col(m) = lm ----
    const int y0 = q * 4;
    #pragma unroll
    for (int kf = 0; kf < 2; ++kf) {
        const int kbase2 = kb + kf * 32 + 4 * hi;
        #pragma unroll
        for (int f = 0; f < 4; ++f) {
            int m  = mb + f * 32 + lm;
            int yy = m >> 6;
            int xx = m & 63;
            float* op = out + (((size_t)(n * 256 + kbase2) * 64) + y0 + yy) * 64 + xx;
            #pragma unroll
            for (int reg = 0; reg < 16; ++reg) {
                int koff = (reg & 3) + 8 * (reg >> 2);
                op[(size_t)koff * 4096] = acc[kf][f][reg];
            }
        }
    }
}

// ---------------- fallback (fp32, known-correct) ----------------
__global__ __launch_bounds__(256, 3)
void conv3x3_f32_kernel(const float* __restrict__ x,
                        const float* __restrict__ w,
                        float* __restrict__ out) {
    __shared__ float xs[16][3][72];
    __shared__ float ws[16][9][64];

    const int t  = threadIdx.x;
    const int kt = blockIdx.x & 3;
    const int y  = (blockIdx.x >> 2) & 63;
    const int n  = blockIdx.x >> 8;

    const int k2   = t >> 3;
    const int xg   = t & 7;
    const int kloc = k2 * 2;
    const int x0   = xg * 8;

    float acc0[8] = {0.f,0.f,0.f,0.f,0.f,0.f,0.f,0.f};
    float acc1[8] = {0.f,0.f,0.f,0.f,0.f,0.f,0.f,0.f};

    const int k0 = kt * 64;

    for (int c0 = 0; c0 < C_IN; c0 += 16) {
        for (int idx = t; idx < 16 * 3 * 66; idx += 256) {
            int col = idx % 66;
            int rc  = idx / 66;
            int r   = rc % 3;
            int c   = rc / 3;
            int gx  = col - 1;
            int gy  = y - 1 + r;
            float v = 0.f;
            if ((unsigned)gx < (unsigned)W_IMG && (unsigned)gy < (unsigned)H_IMG)
                v = x[(((n * C_IN) + c0 + c) * H_IMG + gy) * W_IMG + gx];
            xs[c][r][col] = v;
        }
        for (int idx = t; idx < 64 * 16 * 9; idx += 256) {
            int tap = idx % 9;
            int ck  = idx / 9;
            int c   = ck % 16;
            int k   = ck / 16;
            ws[c][tap][k] = w[((k0 + k) * C_IN + c0 + c) * 9 + tap];
        }
        __syncthreads();

        #pragma unroll 2
        for (int c = 0; c < 16; ++c) {
            #pragma unroll
            for (int r = 0; r < 3; ++r) {
                float xr[10];
                #pragma unroll
                for (int i = 0; i < 10; ++i) xr[i] = xs[c][r][x0 + i];
                #pragma unroll
                for (int s = 0; s < 3; ++s) {
                    float w0 = ws[c][r * 3 + s][kloc];
                    float w1 = ws[c][r * 3 + s][kloc + 1];
                    #pragma unroll
                    for (int i = 0; i < 8; ++i) {
                        acc0[i] = fmaf(w0, xr[i + s], acc0[i]);
                        acc1[i] = fmaf(w1, xr[i + s], acc1[i]);
                    }
                }
            }
        }
        __syncthreads();
    }

    float* o0 = &out[(((n * K_OUT) + k0 + kloc) * H_IMG + y) * W_IMG + x0];
    float* o1 = o0 + H_IMG * W_IMG;
    #pragma unroll
    for (int i = 0; i < 8; ++i) o0[i] = acc0[i];
    #pragma unroll
    for (int i = 0; i < 8; ++i) o1[i] = acc1[i];
}

extern "C" void kernel_launch(void* const* d_in, const int* in_sizes, int n_in,
                              void* d_out, int out_size, void* d_ws, size_t ws_size,
                              hipStream_t stream) {
    const float* x = (const float*)d_in[0];
    const float* w = (const float*)d_in[1];
    float* out = (float*)d_out;
    (void)in_sizes; (void)n_in; (void)out_size;

    if (ws_size >= WS_NEED) {
        __hip_bfloat16* xb = (__hip_bfloat16*)d_ws;
        __hip_bfloat16* wb = (__hip_bfloat16*)((char*)d_ws + XB_BYTES);
        transform_fused_kernel<<<1056 + 256, 256, 0, stream>>>(x, w, xb, wb);
        conv3x3_mfma_kernel<<<256, 512, 0, stream>>>((const char*)xb, (const char*)wb, out);
    } else {
        conv3x3_f32_kernel<<<4096, 256, 0, stream>>>(x, w, out);
    }
}

// Round 6
// 127.272 us; speedup vs baseline: 9.7615x; 1.0443x over previous
//
#include <hip/hip_runtime.h>
#include <hip/hip_bf16.h>
#include <stdint.h>

typedef short bf16x8 __attribute__((ext_vector_type(8)));
typedef float f32x16 __attribute__((ext_vector_type(16)));

#define N_IMG 16
#define C_IN  128
#define H_IMG 64
#define W_IMG 64
#define K_OUT 256

// ws layout: xb = padded NHWC bf16 [16][66][66][128]; wb2 = frag-ordered W bf16:
//   [chunk=tap*4+cc (36)][kgrp (8)][ks (2)][lane (64)][8 bf16]   (16 KB per chunk)
#define XB_BYTES (16ull*66*66*128*2)       // 17,842,176
#define WB_BYTES (36ull*8*2*64*16)         //    589,824
#define WS_NEED  (XB_BYTES + WB_BYTES)

#define LDSX_BYTES (6*66*256)              // 101,376 (X tile, resident, read-only)

__device__ __forceinline__ void gload16(void* lds, const void* g) {
    __builtin_amdgcn_global_load_lds(
        (const __attribute__((address_space(1))) void*)g,
        (__attribute__((address_space(3))) void*)lds, 16, 0, 0);
}

__device__ __forceinline__ uint32_t pack2(float a, float b) {
    __hip_bfloat16 ha = __float2bfloat16(a), hb = __float2bfloat16(b);
    return (uint32_t)*(uint16_t*)&ha | ((uint32_t)*(uint16_t*)&hb << 16);
}

// ---------------- fused prep: x -> padded NHWC bf16, w -> frag-ordered wb2 ------------
// blocks [0,1056): x rows.  blocks [1056,1312): w out-channel groups (one k each).
__global__ __launch_bounds__(256)
void transform_fused_kernel(const float* __restrict__ x, const float* __restrict__ w,
                            __hip_bfloat16* __restrict__ xb, __hip_bfloat16* __restrict__ wb) {
    __shared__ __align__(16) uint32_t xs[64 * 64];   // [row=x][cpair j], XOR-swizzled
    __shared__ float lw[1152];
    const int b = blockIdx.x;
    const int t = threadIdx.x;

    if (b < 1056) {
        const int yt = b % 66;
        const int n  = b / 66;
        const bool interior = (yt >= 1 && yt <= 64);

        if (interior) {
            const float4* src = (const float4*)(x + (size_t)n * 524288 + (size_t)(yt - 1) * 64);
            #pragma unroll
            for (int it = 0; it < 4; ++it) {
                const int x4 = t & 15;                 // float4 index in row (coalesced)
                const int j  = (t >> 4) + it * 16;     // c-pair 0..63
                float4 va = src[(2 * j) * 1024 + x4];
                float4 vb = src[(2 * j + 1) * 1024 + x4];
                const float* pa = (const float*)&va;
                const float* pb = (const float*)&vb;
                #pragma unroll
                for (int i = 0; i < 4; ++i) {
                    int row = x4 * 4 + i;
                    xs[row * 64 + (j ^ (((row >> 2) & 3) << 2))] = pack2(pa[i], pb[i]);
                }
            }
        }
        __syncthreads();

        uint4* dst = (uint4*)((char*)xb + (size_t)(n * 66 + yt) * 66 * 256);
        #pragma unroll
        for (int it = 0; it < 5; ++it) {
            int ch = t + it * 256;
            if (ch < 1056) {
                int xt = ch >> 4, u = ch & 15;
                uint4 val = make_uint4(0u, 0u, 0u, 0u);
                if (interior && xt >= 1 && xt <= 64) {
                    int row = xt - 1;
                    val = *(const uint4*)&xs[row * 64 + 4 * (u ^ ((row >> 2) & 3))];
                }
                dst[ch] = val;
            }
        }
    } else {
        // ---- w path: w[k][c][tap] fp32 -> wb2 frag-ordered ----
        const int kg = b - 1056;                       // this block's out-channel k
        for (int e = t; e < 1152; e += 256) lw[e] = w[kg * 1152 + e];
        __syncthreads();
        const int basek = (kg >> 5) * 1024 + (kg & 31) * 8;   // kgrp*1024 + lm*8 (elements)
        #pragma unroll
        for (int tap = 0; tap < 9; ++tap) {
            if (t < 128) {
                int c = t;
                int idx = (tap * 4 + (c >> 5)) * 8192 + basek
                        + ((c >> 4) & 1) * 512 + ((c >> 3) & 1) * 256 + (c & 7);
                wb[idx] = __float2bfloat16(lw[c * 9 + tap]);
            }
        }
    }
}

// ---------------- main conv: barrier-free K-loop, W from global, X resident ----------
// Block: (n, y-quad) -> 256 k x 256 m (4 y x 64 x). 8 waves, each 64k x 128m.
// Per chunk (tap,cc): 8 X ds_reads (half-chunk pipelined) + 4 coalesced W global
// loads (2 chunks ahead, ping-pong reg sets) + 16 MFMA. No __syncthreads after
// prologue: X LDS tile is read-only, W frags are per-wave registers.
#define CHUNK(CC, AU, XBN)                                                                    \
  {                                                                                           \
    _Pragma("unroll") for (int f = 0; f < 4; ++f)  /* x1 = X(j, ks1) */                       \
      x1[f] = *(const bf16x8*)(lds + (xb0[f] ^ (((CC) << 6) | 32)));                          \
    __builtin_amdgcn_s_setprio(1);                                                            \
    _Pragma("unroll") for (int f = 0; f < 4; ++f) {                                           \
      acc[0][f] = __builtin_amdgcn_mfma_f32_32x32x16_bf16(AU[0][0], x0[f], acc[0][f], 0, 0, 0); \
      acc[1][f] = __builtin_amdgcn_mfma_f32_32x32x16_bf16(AU[1][0], x0[f], acc[1][f], 0, 0, 0); \
    }                                                                                         \
    __builtin_amdgcn_s_setprio(0);                                                            \
    _Pragma("unroll") for (int f = 0; f < 4; ++f)  /* x0 = X(j+1, ks0) */                     \
      x0[f] = *(const bf16x8*)(lds + ((XBN)[f] ^ ((((CC) + 1) & 3) << 6)));                   \
    __builtin_amdgcn_s_setprio(1);                                                            \
    _Pragma("unroll") for (int f = 0; f < 4; ++f) {                                           \
      acc[0][f] = __builtin_amdgcn_mfma_f32_32x32x16_bf16(AU[0][1], x1[f], acc[0][f], 0, 0, 0); \
      acc[1][f] = __builtin_amdgcn_mfma_f32_32x32x16_bf16(AU[1][1], x1[f], acc[1][f], 0, 0, 0); \
    }                                                                                         \
    __builtin_amdgcn_s_setprio(0);                                                            \
    { int jj = tap * 4 + (CC) + 2; if (jj >= 36) jj -= 36;  /* W(j+2) -> AU */                \
      const char* wc = wgw + (size_t)jj * 16384;                                              \
      _Pragma("unroll") for (int kf = 0; kf < 2; ++kf)                                        \
        _Pragma("unroll") for (int ks = 0; ks < 2; ++ks)                                      \
          AU[kf][ks] = *(const bf16x8*)(wc + kf * 2048 + ks * 1024);                          \
    }                                                                                         \
  }

__global__ __launch_bounds__(512, 2)
void conv3x3_mfma_kernel(const char* __restrict__ xg,
                         const char* __restrict__ wg2,
                         float* __restrict__ out) {
    __shared__ uint4 smem[LDSX_BYTES / 16];
    char* lds = (char*)smem;

    const int t    = threadIdx.x;
    const int b    = blockIdx.x;        // 0..255
    const int q    = b & 15;            // y-quad
    const int n    = b >> 4;
    const int lane = t & 63;
    const int wv   = t >> 6;
    const int lm   = lane & 31;
    const int hi   = lane >> 5;
    const int kb   = (wv >> 1) * 64;    // wave k-base
    const int mb   = (wv & 1) * 128;    // wave m-base
    const int hi4  = hi * 16;

    int rc0[4];
    #pragma unroll
    for (int f = 0; f < 4; ++f) {
        int m = mb + f * 32 + lm;
        rc0[f] = (m >> 6) * 66 + (m & 63);
    }

    // ---- prologue: stage X (linear LDS dest, pre-swizzled source) ----
    const char* xsrc = xg + (size_t)(n * 66 + q * 4) * 66 * 256;
    for (int ch = t; ch < 6336; ch += 512) {
        int L = ch * 16;
        gload16(lds + L, xsrc + (L ^ (((L >> 8) & 7) << 4)));
    }

    // ---- prologue: W chunks 0,1 into registers (coalesced, frag-linear layout) ----
    const char* wgw = wg2 + (wv >> 1) * 4096 + lane * 16;
    bf16x8 aA[2][2], aB[2][2];
    #pragma unroll
    for (int kf = 0; kf < 2; ++kf)
        #pragma unroll
        for (int ks = 0; ks < 2; ++ks) {
            aA[kf][ks] = *(const bf16x8*)(wgw + kf * 2048 + ks * 1024);
            aB[kf][ks] = *(const bf16x8*)(wgw + 16384 + kf * 2048 + ks * 1024);
        }

    asm volatile("s_waitcnt vmcnt(0)" ::: "memory");
    __syncthreads();                    // X tile staged; only barrier in the kernel

    f32x16 acc[2][4];
    #pragma unroll
    for (int i = 0; i < 2; ++i)
        #pragma unroll
        for (int j = 0; j < 4; ++j)
            acc[i][j] = (f32x16)(0.f);

    // per-tap X base addresses (ks=0, cc=0); ks/cc fold in by XOR (swizzle-linear)
    int xb0[4], xbN[4];
    #pragma unroll
    for (int f = 0; f < 4; ++f) {
        int rc = rc0[f];                // tap 0: rs66 = 0
        xbN[f] = rc * 256 + (hi4 ^ ((rc & 7) << 4));
    }

    bf16x8 x0[4], x1[4];
    #pragma unroll
    for (int f = 0; f < 4; ++f)
        x0[f] = *(const bf16x8*)(lds + xbN[f]);     // X(chunk 0, ks0)

    for (int tap = 0; tap < 9; ++tap) {
        #pragma unroll
        for (int f = 0; f < 4; ++f) xb0[f] = xbN[f];
        {
            int tn = (tap < 8) ? tap + 1 : 8;       // clamp keeps addresses in-bounds
            int rn = (tn >= 6) ? 2 : (tn >= 3 ? 1 : 0);
            int rs = rn * 66 + (tn - rn * 3);
            #pragma unroll
            for (int f = 0; f < 4; ++f) {
                int rc = rc0[f] + rs;
                xbN[f] = rc * 256 + (hi4 ^ ((rc & 7) << 4));
            }
        }
        CHUNK(0, aA, xb0)
        CHUNK(1, aB, xb0)
        CHUNK(2, aA, xb0)
        CHUNK(3, aB, xbN)
    }

    // ---- epilogue: D row(k) = (reg&3)+8*(reg>>2)+4*hi, col(m) = lm ----
    const int y0 = q * 4;
    #pragma unroll
    for (int kf = 0; kf < 2; ++kf) {
        const int kbase2 = kb + kf * 32 + 4 * hi;
        #pragma unroll
        for (int f = 0; f < 4; ++f) {
            int m  = mb + f * 32 + lm;
            int yy = m >> 6;
            int xx = m & 63;
            float* op = out + (((size_t)(n * 256 + kbase2) * 64) + y0 + yy) * 64 + xx;
            #pragma unroll
            for (int reg = 0; reg < 16; ++reg) {
                int koff = (reg & 3) + 8 * (reg >> 2);
                op[(size_t)koff * 4096] = acc[kf][f][reg];
            }
        }
    }
}

// ---------------- fallback (fp32, known-correct) ----------------
__global__ __launch_bounds__(256, 3)
void conv3x3_f32_kernel(const float* __restrict__ x,
                        const float* __restrict__ w,
                        float* __restrict__ out) {
    __shared__ float xs[16][3][72];
    __shared__ float ws[16][9][64];

    const int t  = threadIdx.x;
    const int kt = blockIdx.x & 3;
    const int y  = (blockIdx.x >> 2) & 63;
    const int n  = blockIdx.x >> 8;

    const int k2   = t >> 3;
    const int xg   = t & 7;
    const int kloc = k2 * 2;
    const int x0   = xg * 8;

    float acc0[8] = {0.f,0.f,0.f,0.f,0.f,0.f,0.f,0.f};
    float acc1[8] = {0.f,0.f,0.f,0.f,0.f,0.f,0.f,0.f};

    const int k0 = kt * 64;

    for (int c0 = 0; c0 < C_IN; c0 += 16) {
        for (int idx = t; idx < 16 * 3 * 66; idx += 256) {
            int col = idx % 66;
            int rc  = idx / 66;
            int r   = rc % 3;
            int c   = rc / 3;
            int gx  = col - 1;
            int gy  = y - 1 + r;
            float v = 0.f;
            if ((unsigned)gx < (unsigned)W_IMG && (unsigned)gy < (unsigned)H_IMG)
                v = x[(((n * C_IN) + c0 + c) * H_IMG + gy) * W_IMG + gx];
            xs[c][r][col] = v;
        }
        for (int idx = t; idx < 64 * 16 * 9; idx += 256) {
            int tap = idx % 9;
            int ck  = idx / 9;
            int c   = ck % 16;
            int k   = ck / 16;
            ws[c][tap][k] = w[((k0 + k) * C_IN + c0 + c) * 9 + tap];
        }
        __syncthreads();

        #pragma unroll 2
        for (int c = 0; c < 16; ++c) {
            #pragma unroll
            for (int r = 0; r < 3; ++r) {
                float xr[10];
                #pragma unroll
                for (int i = 0; i < 10; ++i) xr[i] = xs[c][r][x0 + i];
                #pragma unroll
                for (int s = 0; s < 3; ++s) {
                    float w0 = ws[c][r * 3 + s][kloc];
                    float w1 = ws[c][r * 3 + s][kloc + 1];
                    #pragma unroll
                    for (int i = 0; i < 8; ++i) {
                        acc0[i] = fmaf(w0, xr[i + s], acc0[i]);
                        acc1[i] = fmaf(w1, xr[i + s], acc1[i]);
                    }
                }
            }
        }
        __syncthreads();
    }

    float* o0 = &out[(((n * K_OUT) + k0 + kloc) * H_IMG + y) * W_IMG + x0];
    float* o1 = o0 + H_IMG * W_IMG;
    #pragma unroll
    for (int i = 0; i < 8; ++i) o0[i] = acc0[i];
    #pragma unroll
    for (int i = 0; i < 8; ++i) o1[i] = acc1[i];
}

extern "C" void kernel_launch(void* const* d_in, const int* in_sizes, int n_in,
                              void* d_out, int out_size, void* d_ws, size_t ws_size,
                              hipStream_t stream) {
    const float* x = (const float*)d_in[0];
    const float* w = (const float*)d_in[1];
    float* out = (float*)d_out;
    (void)in_sizes; (void)n_in; (void)out_size;

    if (ws_size >= WS_NEED) {
        __hip_bfloat16* xb = (__hip_bfloat16*)d_ws;
        __hip_bfloat16* wb = (__hip_bfloat16*)((char*)d_ws + XB_BYTES);
        transform_fused_kernel<<<1056 + 256, 256, 0, stream>>>(x, w, xb, wb);
        conv3x3_mfma_kernel<<<256, 512, 0, stream>>>((const char*)xb, (const char*)wb, out);
    } else {
        conv3x3_f32_kernel<<<4096, 256, 0, stream>>>(x, w, out);
    }
}